// Round 2
// baseline (5395.206 us; speedup 1.0000x reference)
//
#include <hip/hip_runtime.h>

#define BB 256
#define TT 256
#define II 256
#define HH 1024
#define LL 128
#define K1 1280   // HH + II
#define GN 3072   // 3*HH

typedef short s8v    __attribute__((ext_vector_type(8)));
typedef float f32x4  __attribute__((ext_vector_type(4)));
typedef float f4v    __attribute__((ext_vector_type(4)));

__device__ __forceinline__ unsigned short f2bf(float f) {
    unsigned u = __float_as_uint(f);
    u += 0x7fffu + ((u >> 16) & 1u);
    return (unsigned short)(u >> 16);
}
__device__ __forceinline__ float bf2f(unsigned short h) {
    return __uint_as_float(((unsigned)h) << 16);
}
__device__ __forceinline__ float sigm(float x) { return 1.0f / (1.0f + __expf(-x)); }

__device__ __forceinline__ s8v cvt8(const float* __restrict__ p) {
    const f4v lo = *(const f4v*)p;
    const f4v hi = *(const f4v*)(p + 4);
    s8v r;
    r[0] = (short)f2bf(lo[0]); r[1] = (short)f2bf(lo[1]);
    r[2] = (short)f2bf(lo[2]); r[3] = (short)f2bf(lo[3]);
    r[4] = (short)f2bf(hi[0]); r[5] = (short)f2bf(hi[1]);
    r[6] = (short)f2bf(hi[2]); r[7] = (short)f2bf(hi[3]);
    return r;
}

// ---- prep: permuted combined gate weights, bf16 ----
// Row o = nt*48 + gate*16 + jj  <-  source gate row gate*HH + (nt*16+jj).
// Cols [0,1024) = W_hh row; [1024,1280) = W_ih row.
__global__ void k_prep_w(const float* __restrict__ Whh, const float* __restrict__ Wih,
                         unsigned short* __restrict__ Wperm) {
    int o = blockIdx.x;                 // 3072
    int ntt = o / 48, q = o - ntt * 48;
    int gate = q >> 4, j = ntt * 16 + (q & 15);
    int src = gate * HH + j;
    const float* sh = Whh + (size_t)src * HH;
    const float* si = Wih + (size_t)src * II;
    unsigned short* dst = Wperm + (size_t)o * K1;
    for (int k = threadIdx.x; k < K1; k += 256)
        dst[k] = f2bf(k < HH ? sh[k] : si[k - HH]);
}

__global__ void k_prep_misc(const float* __restrict__ bih, const float* __restrict__ bhh,
                            const float* __restrict__ Wout,
                            float* __restrict__ bihp, float* __restrict__ bhhp,
                            unsigned short* __restrict__ Woutb) {
    int idx = blockIdx.x * 256 + threadIdx.x;
    if (idx < GN) {
        int ntt = idx / 48, q = idx - ntt * 48;
        int gate = q >> 4, j = ntt * 16 + (q & 15);
        int src = gate * HH + j;
        bihp[idx] = bih[src];
        bhhp[idx] = bhh[src];
    }
    for (size_t i = (size_t)blockIdx.x * 256 + threadIdx.x; i < (size_t)II * HH;
         i += (size_t)gridDim.x * 256)
        Woutb[i] = f2bf(Wout[i]);
}

__global__ void k_h0(const float* __restrict__ z, const float* __restrict__ Wz,
                     const float* __restrict__ bz, unsigned short* __restrict__ hbuf) {
    int b = blockIdx.x >> 2;
    int j = ((blockIdx.x & 3) << 8) + threadIdx.x;
    const f4v* zr = (const f4v*)(z + (size_t)b * LL);
    const f4v* wr = (const f4v*)(Wz + (size_t)j * LL);
    float s = bz[j];
#pragma unroll
    for (int i = 0; i < LL / 4; ++i) {
        f4v a = zr[i], w = wr[i];
        s += a[0] * w[0] + a[1] * w[1] + a[2] * w[2] + a[3] * w[3];
    }
    hbuf[(size_t)b * HH + j] = f2bf(tanhf(s));
}

// output projection for one 16x16 tile, K=1024 split across 4 waves
__device__ __forceinline__ void proj_tile(
    const unsigned short* __restrict__ hb, const unsigned short* __restrict__ Woutb,
    float* __restrict__ out, float (*pred)[256],
    int bo, int io, int wave, int lane, int lr, int lk, int tp, float boutv) {
    f32x4 oa = {0.f, 0.f, 0.f, 0.f};
    const unsigned short* ap = hb + (size_t)(bo * 16 + lr) * HH + (wave << 8) + lk;
    const unsigned short* wp = Woutb + (size_t)(io * 16 + lr) * HH + (wave << 8) + lk;
#pragma unroll
    for (int ks = 0; ks < 8; ++ks) {
        s8v a = *(const s8v*)(ap + ks * 32);
        s8v w = *(const s8v*)(wp + ks * 32);
        oa = __builtin_amdgcn_mfma_f32_16x16x32_bf16(a, w, oa, 0, 0, 0);
    }
    if (wave >= 1) {
#pragma unroll
        for (int r = 0; r < 4; ++r)
            pred[wave - 1][(((lane >> 4) << 2) + r) * 16 + lr] = oa[r];
    }
    __syncthreads();
    if (wave == 0) {
#pragma unroll
        for (int r = 0; r < 4; ++r) {
            int rw = ((lane >> 4) << 2) + r;
            int idx = rw * 16 + lr;
            float v = oa[r] + pred[0][idx] + pred[1][idx] + pred[2][idx] + boutv;
            out[(size_t)(bo * 16 + rw) * (TT * II) + (size_t)tp * II + io * 16 + lr] = sigm(v);
        }
    }
}

// ---- main persistent GRU kernel (plain launch, custom m-group barriers) ----
// grid 256 = 4 m-groups x 64 nt. WG = 64 batches x 48 gate rows (16 hidden j).
__global__ __launch_bounds__(256, 1) void dec_main(
    const float* __restrict__ tgt,
    const unsigned short* __restrict__ Wperm,
    const float* __restrict__ bihp, const float* __restrict__ bhhp,
    unsigned short* __restrict__ hbuf,
    const unsigned short* __restrict__ Woutb,
    const float* __restrict__ bout,
    float* __restrict__ out,
    unsigned* __restrict__ barr) {
    __shared__ float red[3][3072];   // [set][64 rows x 48 cols]
    __shared__ float gxn[1024];      // [64 rows x 16 cols] x-part of n-gate
    __shared__ float pred[3][256];   // projection reduce

    const int tid = threadIdx.x;
    const int wave = tid >> 6, lane = tid & 63;
    const int lr = lane & 15;
    const int lk = (lane >> 4) << 3;
    const int bid = blockIdx.x;
    const int m = bid >> 6, nt = bid & 63;      // same-nt WGs share XCD (bid%8)
    const int bo = (m << 2) + (nt >> 4), io = nt & 15;

    const int ejj = tid & 15;
    const int ob = nt * 48;
    const float bi_r  = bihp[ob + ejj] + bhhp[ob + ejj];
    const float bi_z  = bihp[ob + 16 + ejj] + bhhp[ob + 16 + ejj];
    const float bi_xn = bihp[ob + 32 + ejj];
    const float bi_hn = bhhp[ob + 32 + ejj];
    const float boutv = bout[io * 16 + lr];

    unsigned* mybarr = barr + m * TT;

    for (int t = 0; t < TT; ++t) {
        const unsigned short* hcur = hbuf + (size_t)(t % 3) * (BB * HH);
        unsigned short* hnxt = hbuf + (size_t)((t + 1) % 3) * (BB * HH);

        f32x4 acc[12];
#pragma unroll
        for (int i = 0; i < 12; ++i) acc[i] = (f32x4){0.f, 0.f, 0.f, 0.f};

        if (wave < 3) {
            const int kb = wave * 320;
            const unsigned short* hp0 = hcur + (size_t)(m * 64 + lr) * HH + kb + lk;
            const unsigned short* wp0 = Wperm + (size_t)(nt * 48 + lr) * K1 + kb + lk;
#pragma unroll
            for (int ks = 0; ks < 10; ++ks) {
                s8v a[4], w[3];
#pragma unroll
                for (int mi = 0; mi < 4; ++mi)
                    a[mi] = *(const s8v*)(hp0 + (size_t)mi * 16 * HH + ks * 32);
#pragma unroll
                for (int ni = 0; ni < 3; ++ni)
                    w[ni] = *(const s8v*)(wp0 + (size_t)ni * 16 * K1 + ks * 32);
#pragma unroll
                for (int mi = 0; mi < 4; ++mi)
#pragma unroll
                    for (int ni = 0; ni < 3; ++ni)
                        acc[mi * 3 + ni] = __builtin_amdgcn_mfma_f32_16x16x32_bf16(
                            a[mi], w[ni], acc[mi * 3 + ni], 0, 0, 0);
            }
        } else {
            f32x4 accx[4];
#pragma unroll
            for (int i = 0; i < 4; ++i) accx[i] = (f32x4){0.f, 0.f, 0.f, 0.f};
            // h-part: k in [960,1024)
            {
                const unsigned short* hp0 = hcur + (size_t)(m * 64 + lr) * HH + 960 + lk;
                const unsigned short* wp0 = Wperm + (size_t)(nt * 48 + lr) * K1 + 960 + lk;
#pragma unroll
                for (int ks = 0; ks < 2; ++ks) {
                    s8v a[4], w[3];
#pragma unroll
                    for (int mi = 0; mi < 4; ++mi)
                        a[mi] = *(const s8v*)(hp0 + (size_t)mi * 16 * HH + ks * 32);
#pragma unroll
                    for (int ni = 0; ni < 3; ++ni)
                        w[ni] = *(const s8v*)(wp0 + (size_t)ni * 16 * K1 + ks * 32);
#pragma unroll
                    for (int mi = 0; mi < 4; ++mi)
#pragma unroll
                        for (int ni = 0; ni < 3; ++ni)
                            acc[mi * 3 + ni] = __builtin_amdgcn_mfma_f32_16x16x32_bf16(
                                a[mi], w[ni], acc[mi * 3 + ni], 0, 0, 0);
                }
            }
            // x-part: k' in [0,256), f32 target converted in-register.
            // r,z cols fold into acc; n col goes to accx (r gates it later).
            {
                const float* xp0 = tgt + ((size_t)(m * 64 + lr) * TT + t) * II + lk;
                const unsigned short* wp0 = Wperm + (size_t)(nt * 48 + lr) * K1 + HH + lk;
#pragma unroll
                for (int ks = 0; ks < 8; ++ks) {
                    s8v a[4], w[3];
#pragma unroll
                    for (int mi = 0; mi < 4; ++mi)
                        a[mi] = cvt8(xp0 + (size_t)mi * 16 * TT * II + ks * 32);
#pragma unroll
                    for (int ni = 0; ni < 3; ++ni)
                        w[ni] = *(const s8v*)(wp0 + (size_t)ni * 16 * K1 + ks * 32);
#pragma unroll
                    for (int mi = 0; mi < 4; ++mi) {
                        acc[mi * 3 + 0] = __builtin_amdgcn_mfma_f32_16x16x32_bf16(a[mi], w[0], acc[mi * 3 + 0], 0, 0, 0);
                        acc[mi * 3 + 1] = __builtin_amdgcn_mfma_f32_16x16x32_bf16(a[mi], w[1], acc[mi * 3 + 1], 0, 0, 0);
                        accx[mi]        = __builtin_amdgcn_mfma_f32_16x16x32_bf16(a[mi], w[2], accx[mi], 0, 0, 0);
                    }
                }
            }
#pragma unroll
            for (int mi = 0; mi < 4; ++mi)
#pragma unroll
                for (int r = 0; r < 4; ++r)
                    gxn[(mi * 16 + ((lane >> 4) << 2) + r) * 16 + lr] = accx[mi][r];
        }

        // cross-wave reduce
        if (wave >= 1) {
            float* s = &red[wave - 1][0];
#pragma unroll
            for (int mi = 0; mi < 4; ++mi)
#pragma unroll
                for (int ni = 0; ni < 3; ++ni)
#pragma unroll
                    for (int r = 0; r < 4; ++r)
                        s[(mi * 16 + ((lane >> 4) << 2) + r) * 48 + ni * 16 + lr] =
                            acc[mi * 3 + ni][r];
        }
        __syncthreads();
        if (wave == 0) {
#pragma unroll
            for (int mi = 0; mi < 4; ++mi)
#pragma unroll
                for (int ni = 0; ni < 3; ++ni)
#pragma unroll
                    for (int r = 0; r < 4; ++r) {
                        int idx = (mi * 16 + ((lane >> 4) << 2) + r) * 48 + ni * 16 + lr;
                        red[0][idx] = acc[mi * 3 + ni][r] + red[0][idx] + red[1][idx] + red[2][idx];
                    }
        }
        __syncthreads();

        // gate epilogue: h_new for 64 batches x 16 j
        {
            const int b0t = tid >> 4;
#pragma unroll
            for (int it = 0; it < 4; ++it) {
                int b = b0t + it * 16;
                float ghr = red[0][b * 48 + ejj];
                float ghz = red[0][b * 48 + 16 + ejj];
                float ghn = red[0][b * 48 + 32 + ejj];
                float gx  = gxn[b * 16 + ejj];
                float r   = sigm(ghr + bi_r);
                float zg  = sigm(ghz + bi_z);
                float n   = tanhf(gx + bi_xn + r * (ghn + bi_hn));
                int bg = m * 64 + b, jg = nt * 16 + ejj;
                float hold = bf2f(hcur[(size_t)bg * HH + jg]);
                hnxt[(size_t)bg * HH + jg] = f2bf((1.f - zg) * n + zg * hold);
            }
        }

        // arrive(t): release h_{t+1}
        __syncthreads();
        if (tid == 0)
            __hip_atomic_fetch_add(mybarr + t, 1u, __ATOMIC_RELEASE, __HIP_MEMORY_SCOPE_AGENT);

        // hide barrier latency: project y_{t-1} from h_t (already synced at t-1)
        if (t > 0)
            proj_tile(hcur, Woutb, out, pred, bo, io, wave, lane, lr, lk, t - 1, boutv);

        // wait(t): all 64 WGs of this m-group arrived
        if (tid == 0) {
            int guard = 0;
            while (__hip_atomic_load(mybarr + t, __ATOMIC_RELAXED,
                                     __HIP_MEMORY_SCOPE_AGENT) < 64u) {
                __builtin_amdgcn_s_sleep(1);
                if (++guard > (1 << 17)) break;   // safety valve: no hang
            }
            __builtin_amdgcn_fence(__ATOMIC_ACQUIRE, "agent");
        }
        __syncthreads();
    }
    // final projection: y_{T-1} from h_T
    proj_tile(hbuf + (size_t)(TT % 3) * (BB * HH), Woutb, out, pred,
              bo, io, wave, lane, lr, lk, TT - 1, boutv);
}

extern "C" void kernel_launch(void* const* d_in, const int* in_sizes, int n_in,
                              void* d_out, int out_size, void* d_ws, size_t ws_size,
                              hipStream_t stream) {
    const float* z    = (const float*)d_in[0];
    const float* tgt  = (const float*)d_in[2];
    const float* Wz2h = (const float*)d_in[3];
    const float* bz2h = (const float*)d_in[4];
    const float* Wih  = (const float*)d_in[5];
    const float* Whh  = (const float*)d_in[6];
    const float* bih  = (const float*)d_in[7];
    const float* bhh  = (const float*)d_in[8];
    const float* Wout = (const float*)d_in[9];
    const float* bout = (const float*)d_in[10];
    float* out = (float*)d_out;

    char* ws = (char*)d_ws;
    unsigned short* Wperm = (unsigned short*)ws;               // 7,864,320
    float* bihp           = (float*)(ws + 7864320);            //    12,288
    float* bhhp           = (float*)(ws + 7876608);            //    12,288
    unsigned short* Woutb = (unsigned short*)(ws + 7888896);   //   524,288
    unsigned short* hbuf  = (unsigned short*)(ws + 8413184);   // 1,572,864 (3 bufs)
    unsigned* barr        = (unsigned*)(ws + 9986048);         //     4,096
    // total ws use: 9,990,144 bytes

    hipMemsetAsync(barr, 0, 4 * TT * sizeof(unsigned), stream);
    hipLaunchKernelGGL(k_prep_w, dim3(GN), dim3(256), 0, stream, Whh, Wih, Wperm);
    hipLaunchKernelGGL(k_prep_misc, dim3(1024), dim3(256), 0, stream, bih, bhh, Wout,
                       bihp, bhhp, Woutb);
    hipLaunchKernelGGL(k_h0, dim3(BB * 4), dim3(256), 0, stream, z, Wz2h, bz2h, hbuf);
    hipLaunchKernelGGL(dec_main, dim3(256), dim3(256), 0, stream,
                       tgt, Wperm, bihp, bhhp, hbuf, Woutb, bout, out, barr);
}

// Round 3
// 5286.334 us; speedup vs baseline: 1.0206x; 1.0206x over previous
//
#include <hip/hip_runtime.h>

#define BB 256
#define TT 256
#define II 256
#define HH 1024
#define LL 128
#define K1 1280   // HH + II
#define GN 3072   // 3*HH

#define RP 52     // red row stride (pad: 4-row groups land 16 banks apart)
#define GP 20     // gxn row stride
#define PP 20     // pred row stride

typedef short s8v    __attribute__((ext_vector_type(8)));
typedef float f32x4  __attribute__((ext_vector_type(4)));
typedef float f4v    __attribute__((ext_vector_type(4)));
typedef unsigned long long u64;

__device__ __forceinline__ unsigned short f2bf(float f) {
    unsigned u = __float_as_uint(f);
    u += 0x7fffu + ((u >> 16) & 1u);
    return (unsigned short)(u >> 16);
}
__device__ __forceinline__ float bf2f(unsigned short h) {
    return __uint_as_float(((unsigned)h) << 16);
}
__device__ __forceinline__ float sigm(float x) { return 1.0f / (1.0f + __expf(-x)); }

// agent-scope (cross-XCD coherent) h access: bypasses stale L1/L2, no fences
__device__ __forceinline__ u64 hload8(const unsigned short* p) {
    return __hip_atomic_load((const u64*)p, __ATOMIC_RELAXED, __HIP_MEMORY_SCOPE_AGENT);
}
__device__ __forceinline__ s8v hload16(const unsigned short* p) {
    union { u64 q[2]; s8v v; } u;
    u.q[0] = __hip_atomic_load((const u64*)p, __ATOMIC_RELAXED, __HIP_MEMORY_SCOPE_AGENT);
    u.q[1] = __hip_atomic_load((const u64*)p + 1, __ATOMIC_RELAXED, __HIP_MEMORY_SCOPE_AGENT);
    return u.v;
}
__device__ __forceinline__ void hstore8(unsigned short* p, u64 v) {
    __hip_atomic_store((u64*)p, v, __ATOMIC_RELAXED, __HIP_MEMORY_SCOPE_AGENT);
}

__device__ __forceinline__ s8v cvt8(const float* __restrict__ p) {
    const f4v lo = *(const f4v*)p;
    const f4v hi = *(const f4v*)(p + 4);
    s8v r;
    r[0] = (short)f2bf(lo[0]); r[1] = (short)f2bf(lo[1]);
    r[2] = (short)f2bf(lo[2]); r[3] = (short)f2bf(lo[3]);
    r[4] = (short)f2bf(hi[0]); r[5] = (short)f2bf(hi[1]);
    r[6] = (short)f2bf(hi[2]); r[7] = (short)f2bf(hi[3]);
    return r;
}

// ---- prep: permuted combined gate weights, bf16 ----
__global__ void k_prep_w(const float* __restrict__ Whh, const float* __restrict__ Wih,
                         unsigned short* __restrict__ Wperm) {
    int o = blockIdx.x;                 // 3072
    int ntt = o / 48, q = o - ntt * 48;
    int gate = q >> 4, j = ntt * 16 + (q & 15);
    int src = gate * HH + j;
    const float* sh = Whh + (size_t)src * HH;
    const float* si = Wih + (size_t)src * II;
    unsigned short* dst = Wperm + (size_t)o * K1;
    for (int k = threadIdx.x; k < K1; k += 256)
        dst[k] = f2bf(k < HH ? sh[k] : si[k - HH]);
}

__global__ void k_prep_misc(const float* __restrict__ bih, const float* __restrict__ bhh,
                            const float* __restrict__ Wout,
                            float* __restrict__ bihp, float* __restrict__ bhhp,
                            unsigned short* __restrict__ Woutb) {
    int idx = blockIdx.x * 256 + threadIdx.x;
    if (idx < GN) {
        int ntt = idx / 48, q = idx - ntt * 48;
        int gate = q >> 4, j = ntt * 16 + (q & 15);
        int src = gate * HH + j;
        bihp[idx] = bih[src];
        bhhp[idx] = bhh[src];
    }
    for (size_t i = (size_t)blockIdx.x * 256 + threadIdx.x; i < (size_t)II * HH;
         i += (size_t)gridDim.x * 256)
        Woutb[i] = f2bf(Wout[i]);
}

__global__ void k_h0(const float* __restrict__ z, const float* __restrict__ Wz,
                     const float* __restrict__ bz, unsigned short* __restrict__ hbuf) {
    int b = blockIdx.x;                 // 256
    int j0 = threadIdx.x * 4;           // 256 threads x 4 j
    const f4v* zr = (const f4v*)(z + (size_t)b * LL);
    u64 packed = 0;
#pragma unroll
    for (int jj = 0; jj < 4; ++jj) {
        int j = j0 + jj;
        const f4v* wr = (const f4v*)(Wz + (size_t)j * LL);
        float s = bz[j];
#pragma unroll
        for (int i = 0; i < LL / 4; ++i) {
            f4v a = zr[i], w = wr[i];
            s += a[0] * w[0] + a[1] * w[1] + a[2] * w[2] + a[3] * w[3];
        }
        packed |= (u64)f2bf(tanhf(s)) << (16 * jj);
    }
    hstore8(hbuf + (size_t)b * HH + j0, packed);
}

// output projection for one 16x16 tile, K=1024 split across 4 waves
__device__ __forceinline__ void proj_tile(
    const unsigned short* __restrict__ hb, const unsigned short* __restrict__ Woutb,
    float* __restrict__ out, float (*pred)[16 * PP],
    int bo, int io, int wave, int lane, int lr, int lk, int tp, float boutv) {
    f32x4 oa = {0.f, 0.f, 0.f, 0.f};
    const unsigned short* ap = hb + (size_t)(bo * 16 + lr) * HH + (wave << 8) + lk;
    const unsigned short* wp = Woutb + (size_t)(io * 16 + lr) * HH + (wave << 8) + lk;
#pragma unroll
    for (int ks = 0; ks < 8; ++ks) {
        s8v a = hload16(ap + ks * 32);
        s8v w = *(const s8v*)(wp + ks * 32);
        oa = __builtin_amdgcn_mfma_f32_16x16x32_bf16(a, w, oa, 0, 0, 0);
    }
    if (wave >= 1) {
#pragma unroll
        for (int r = 0; r < 4; ++r)
            pred[wave - 1][(((lane >> 4) << 2) + r) * PP + lr] = oa[r];
    }
    __syncthreads();
    if (wave == 0) {
#pragma unroll
        for (int r = 0; r < 4; ++r) {
            int rw = ((lane >> 4) << 2) + r;
            int idx = rw * PP + lr;
            float v = oa[r] + pred[0][idx] + pred[1][idx] + pred[2][idx] + boutv;
            out[(size_t)(bo * 16 + rw) * (TT * II) + (size_t)tp * II + io * 16 + lr] = sigm(v);
        }
    }
}

// ---- main persistent GRU kernel (plain launch, m-group barriers, no fences) ----
// grid 256 = 4 m-groups x 64 nt. WG = 64 batches x 48 gate rows (16 hidden j).
__global__ __launch_bounds__(256, 1) void dec_main(
    const float* __restrict__ tgt,
    const unsigned short* __restrict__ Wperm,
    const float* __restrict__ bihp, const float* __restrict__ bhhp,
    unsigned short* __restrict__ hbuf,
    const unsigned short* __restrict__ Woutb,
    const float* __restrict__ bout,
    float* __restrict__ out,
    unsigned* __restrict__ barr) {
    __shared__ float red[3][64 * RP];
    __shared__ float gxn[64 * GP];
    __shared__ float pred[3][16 * PP];

    const int tid = threadIdx.x;
    const int wave = tid >> 6, lane = tid & 63;
    const int lr = lane & 15;
    const int lk = (lane >> 4) << 3;
    const int bid = blockIdx.x;
    const int m = bid >> 6, nt = bid & 63;      // same-nt WGs share XCD (bid%8)
    const int bo = (m << 2) + (nt >> 4), io = nt & 15;

    // epilogue ownership: batch eb, 4 consecutive j starting at ej4
    const int eb = tid & 63;
    const int ej4 = (tid >> 6) << 2;
    const int ob = nt * 48;
    float bir[4], biz[4], bixn[4], bihn[4];
#pragma unroll
    for (int jj = 0; jj < 4; ++jj) {
        int j = ej4 + jj;
        bir[jj]  = bihp[ob + j] + bhhp[ob + j];
        biz[jj]  = bihp[ob + 16 + j] + bhhp[ob + 16 + j];
        bixn[jj] = bihp[ob + 32 + j];
        bihn[jj] = bhhp[ob + 32 + j];
    }
    const float boutv = bout[io * 16 + lr];

    unsigned* mybarr = barr + m * TT;

    for (int t = 0; t < TT; ++t) {
        const unsigned short* hcur = hbuf + (size_t)(t % 3) * (BB * HH);
        unsigned short* hnxt = hbuf + (size_t)((t + 1) % 3) * (BB * HH);

        f32x4 acc[12];
#pragma unroll
        for (int i = 0; i < 12; ++i) acc[i] = (f32x4){0.f, 0.f, 0.f, 0.f};

        if (wave < 3) {
            const int kb = wave * 320;
            const unsigned short* hp0 = hcur + (size_t)(m * 64 + lr) * HH + kb + lk;
            const unsigned short* wp0 = Wperm + (size_t)(nt * 48 + lr) * K1 + kb + lk;
#pragma unroll
            for (int ks = 0; ks < 10; ++ks) {
                s8v a[4], w[3];
#pragma unroll
                for (int mi = 0; mi < 4; ++mi)
                    a[mi] = hload16(hp0 + (size_t)mi * 16 * HH + ks * 32);
#pragma unroll
                for (int ni = 0; ni < 3; ++ni)
                    w[ni] = *(const s8v*)(wp0 + (size_t)ni * 16 * K1 + ks * 32);
#pragma unroll
                for (int mi = 0; mi < 4; ++mi)
#pragma unroll
                    for (int ni = 0; ni < 3; ++ni)
                        acc[mi * 3 + ni] = __builtin_amdgcn_mfma_f32_16x16x32_bf16(
                            a[mi], w[ni], acc[mi * 3 + ni], 0, 0, 0);
            }
        } else {
            f32x4 accx[4];
#pragma unroll
            for (int i = 0; i < 4; ++i) accx[i] = (f32x4){0.f, 0.f, 0.f, 0.f};
            // h-part: k in [960,1024)
            {
                const unsigned short* hp0 = hcur + (size_t)(m * 64 + lr) * HH + 960 + lk;
                const unsigned short* wp0 = Wperm + (size_t)(nt * 48 + lr) * K1 + 960 + lk;
#pragma unroll
                for (int ks = 0; ks < 2; ++ks) {
                    s8v a[4], w[3];
#pragma unroll
                    for (int mi = 0; mi < 4; ++mi)
                        a[mi] = hload16(hp0 + (size_t)mi * 16 * HH + ks * 32);
#pragma unroll
                    for (int ni = 0; ni < 3; ++ni)
                        w[ni] = *(const s8v*)(wp0 + (size_t)ni * 16 * K1 + ks * 32);
#pragma unroll
                    for (int mi = 0; mi < 4; ++mi)
#pragma unroll
                        for (int ni = 0; ni < 3; ++ni)
                            acc[mi * 3 + ni] = __builtin_amdgcn_mfma_f32_16x16x32_bf16(
                                a[mi], w[ni], acc[mi * 3 + ni], 0, 0, 0);
                }
            }
            // x-part: k' in [0,256), f32 target converted in-register.
            {
                const float* xp0 = tgt + ((size_t)(m * 64 + lr) * TT + t) * II + lk;
                const unsigned short* wp0 = Wperm + (size_t)(nt * 48 + lr) * K1 + HH + lk;
#pragma unroll
                for (int ks = 0; ks < 8; ++ks) {
                    s8v a[4], w[3];
#pragma unroll
                    for (int mi = 0; mi < 4; ++mi)
                        a[mi] = cvt8(xp0 + (size_t)mi * 16 * TT * II + ks * 32);
#pragma unroll
                    for (int ni = 0; ni < 3; ++ni)
                        w[ni] = *(const s8v*)(wp0 + (size_t)ni * 16 * K1 + ks * 32);
#pragma unroll
                    for (int mi = 0; mi < 4; ++mi) {
                        acc[mi * 3 + 0] = __builtin_amdgcn_mfma_f32_16x16x32_bf16(a[mi], w[0], acc[mi * 3 + 0], 0, 0, 0);
                        acc[mi * 3 + 1] = __builtin_amdgcn_mfma_f32_16x16x32_bf16(a[mi], w[1], acc[mi * 3 + 1], 0, 0, 0);
                        accx[mi]        = __builtin_amdgcn_mfma_f32_16x16x32_bf16(a[mi], w[2], accx[mi], 0, 0, 0);
                    }
                }
            }
#pragma unroll
            for (int mi = 0; mi < 4; ++mi)
#pragma unroll
                for (int r = 0; r < 4; ++r)
                    gxn[(mi * 16 + ((lane >> 4) << 2) + r) * GP + lr] = accx[mi][r];
        }

        // cross-wave reduce
        if (wave >= 1) {
            float* s = &red[wave - 1][0];
#pragma unroll
            for (int mi = 0; mi < 4; ++mi)
#pragma unroll
                for (int ni = 0; ni < 3; ++ni)
#pragma unroll
                    for (int r = 0; r < 4; ++r)
                        s[(mi * 16 + ((lane >> 4) << 2) + r) * RP + ni * 16 + lr] =
                            acc[mi * 3 + ni][r];
        }
        __syncthreads();
        if (wave == 0) {
#pragma unroll
            for (int mi = 0; mi < 4; ++mi)
#pragma unroll
                for (int ni = 0; ni < 3; ++ni)
#pragma unroll
                    for (int r = 0; r < 4; ++r) {
                        int idx = (mi * 16 + ((lane >> 4) << 2) + r) * RP + ni * 16 + lr;
                        red[0][idx] = acc[mi * 3 + ni][r] + red[0][idx] + red[1][idx] + red[2][idx];
                    }
        }
        __syncthreads();

        // gate epilogue: thread (eb, ej4..ej4+3) -> one packed 8B h store
        {
            const int bg = m * 64 + eb;
            const int jbase = nt * 16 + ej4;
            u64 hold8 = hload8(hcur + (size_t)bg * HH + jbase);
            u64 packed = 0;
#pragma unroll
            for (int jj = 0; jj < 4; ++jj) {
                int c = ej4 + jj;
                float ghr = red[0][eb * RP + c];
                float ghz = red[0][eb * RP + 16 + c];
                float ghn = red[0][eb * RP + 32 + c];
                float gx  = gxn[eb * GP + c];
                float r   = sigm(ghr + bir[jj]);
                float zg  = sigm(ghz + biz[jj]);
                float n   = tanhf(gx + bixn[jj] + r * (ghn + bihn[jj]));
                float hold = bf2f((unsigned short)(hold8 >> (16 * jj)));
                float hnew = (1.f - zg) * n + zg * hold;
                packed |= (u64)f2bf(hnew) << (16 * jj);
            }
            hstore8(hnxt + (size_t)bg * HH + jbase, packed);
        }

        // arrive(t): drain own stores, block-sync, then relaxed signal
        asm volatile("s_waitcnt vmcnt(0)" ::: "memory");
        __syncthreads();
        if (tid == 0)
            __hip_atomic_fetch_add(mybarr + t, 1u, __ATOMIC_RELAXED, __HIP_MEMORY_SCOPE_AGENT);

        // hide barrier latency: project y_{t-1} from h_t (synced at t-1)
        if (t > 0)
            proj_tile(hcur, Woutb, out, pred, bo, io, wave, lane, lr, lk, t - 1, boutv);

        // wait(t): all 64 WGs of this m-group arrived (relaxed poll, no fence)
        if (tid == 0) {
            int guard = 0;
            while (__hip_atomic_load(mybarr + t, __ATOMIC_RELAXED,
                                     __HIP_MEMORY_SCOPE_AGENT) < 64u) {
                __builtin_amdgcn_s_sleep(1);
                if (++guard > (1 << 17)) break;   // safety valve: no hang
            }
        }
        __syncthreads();
    }
    // final projection: y_{T-1} from h_T
    proj_tile(hbuf + (size_t)(TT % 3) * (BB * HH), Woutb, out, pred,
              bo, io, wave, lane, lr, lk, TT - 1, boutv);
}

extern "C" void kernel_launch(void* const* d_in, const int* in_sizes, int n_in,
                              void* d_out, int out_size, void* d_ws, size_t ws_size,
                              hipStream_t stream) {
    const float* z    = (const float*)d_in[0];
    const float* tgt  = (const float*)d_in[2];
    const float* Wz2h = (const float*)d_in[3];
    const float* bz2h = (const float*)d_in[4];
    const float* Wih  = (const float*)d_in[5];
    const float* Whh  = (const float*)d_in[6];
    const float* bih  = (const float*)d_in[7];
    const float* bhh  = (const float*)d_in[8];
    const float* Wout = (const float*)d_in[9];
    const float* bout = (const float*)d_in[10];
    float* out = (float*)d_out;

    char* ws = (char*)d_ws;
    unsigned short* Wperm = (unsigned short*)ws;               // 7,864,320
    float* bihp           = (float*)(ws + 7864320);            //    12,288
    float* bhhp           = (float*)(ws + 7876608);            //    12,288
    unsigned short* Woutb = (unsigned short*)(ws + 7888896);   //   524,288
    unsigned short* hbuf  = (unsigned short*)(ws + 8413184);   // 1,572,864 (3 bufs)
    unsigned* barr        = (unsigned*)(ws + 9986048);         //     4,096
    // total ws use: 9,990,144 bytes

    hipMemsetAsync(barr, 0, 4 * TT * sizeof(unsigned), stream);
    hipLaunchKernelGGL(k_prep_w, dim3(GN), dim3(256), 0, stream, Whh, Wih, Wperm);
    hipLaunchKernelGGL(k_prep_misc, dim3(1024), dim3(256), 0, stream, bih, bhh, Wout,
                       bihp, bhhp, Woutb);
    hipLaunchKernelGGL(k_h0, dim3(BB), dim3(256), 0, stream, z, Wz2h, bz2h, hbuf);
    hipLaunchKernelGGL(dec_main, dim3(256), dim3(256), 0, stream,
                       tgt, Wperm, bihp, bhhp, hbuf, Woutb, bout, out, barr);
}

// Round 5
// 5168.284 us; speedup vs baseline: 1.0439x; 1.0228x over previous
//
#include <hip/hip_runtime.h>

#define BB 256
#define TT 256
#define II 256
#define HH 1024
#define LL 128
#define K1 1280   // HH + II
#define GN 3072   // 3*HH

#define RP 52     // red row stride (floats)
#define GP 20     // gxn row stride
#define PP 20     // pred row stride

typedef short s8v    __attribute__((ext_vector_type(8)));
typedef float f32x4  __attribute__((ext_vector_type(4)));
typedef float f4v    __attribute__((ext_vector_type(4)));
typedef unsigned long long u64;

__device__ __forceinline__ unsigned short f2bf(float f) {
    unsigned u = __float_as_uint(f);
    u += 0x7fffu + ((u >> 16) & 1u);
    return (unsigned short)(u >> 16);
}
__device__ __forceinline__ float bf2f(unsigned short h) {
    return __uint_as_float(((unsigned)h) << 16);
}
__device__ __forceinline__ float sigm(float x) { return 1.0f / (1.0f + __expf(-x)); }

__device__ __forceinline__ s8v cvt8(const float* __restrict__ p) {
    const f4v lo = *(const f4v*)p;
    const f4v hi = *(const f4v*)(p + 4);
    s8v r;
    r[0] = (short)f2bf(lo[0]); r[1] = (short)f2bf(lo[1]);
    r[2] = (short)f2bf(lo[2]); r[3] = (short)f2bf(lo[3]);
    r[4] = (short)f2bf(hi[0]); r[5] = (short)f2bf(hi[1]);
    r[6] = (short)f2bf(hi[2]); r[7] = (short)f2bf(hi[3]);
    return r;
}

// sc1 loads (L3-coherent) for non-FRESH mode
__device__ __forceinline__ s8v hload16a(const unsigned short* p) {
    union { u64 q[2]; s8v v; } u;
    u.q[0] = __hip_atomic_load((const u64*)p, __ATOMIC_RELAXED, __HIP_MEMORY_SCOPE_AGENT);
    u.q[1] = __hip_atomic_load((const u64*)p + 1, __ATOMIC_RELAXED, __HIP_MEMORY_SCOPE_AGENT);
    return u.v;
}
// FRESH=1: slot-per-step h, plain loads (addresses never stale). FRESH=0: sc1 loads.
template<int FRESH> __device__ __forceinline__ s8v ld16h(const unsigned short* p) {
    if constexpr (FRESH) return *(const s8v*)p;
    else return hload16a(p);
}
template<int FRESH> __device__ __forceinline__ unsigned ld4h(const unsigned short* p) {
    if constexpr (FRESH) return *(const unsigned*)p;
    else return __hip_atomic_load((const unsigned*)p, __ATOMIC_RELAXED, __HIP_MEMORY_SCOPE_AGENT);
}
// h stores are ALWAYS sc1 (truth lives in L3, readable from any XCD)
__device__ __forceinline__ void st4h(unsigned short* p, unsigned v) {
    __hip_atomic_store((unsigned*)p, v, __ATOMIC_RELAXED, __HIP_MEMORY_SCOPE_AGENT);
}

// ---- prep kernels ----
__global__ void k_prep_w(const float* __restrict__ Whh, const float* __restrict__ Wih,
                         unsigned short* __restrict__ Wperm) {
    int o = blockIdx.x;                 // 3072
    int ntt = o / 48, q = o - ntt * 48;
    int gate = q >> 4, j = ntt * 16 + (q & 15);
    int src = gate * HH + j;
    const float* sh = Whh + (size_t)src * HH;
    const float* si = Wih + (size_t)src * II;
    unsigned short* dst = Wperm + (size_t)o * K1;
    for (int k = threadIdx.x; k < K1; k += 256)
        dst[k] = f2bf(k < HH ? sh[k] : si[k - HH]);
}

__global__ void k_prep_misc(const float* __restrict__ bih, const float* __restrict__ bhh,
                            const float* __restrict__ Wout,
                            float* __restrict__ bihp, float* __restrict__ bhhp,
                            unsigned short* __restrict__ Woutb) {
    int idx = blockIdx.x * 256 + threadIdx.x;
    if (idx < GN) {
        int ntt = idx / 48, q = idx - ntt * 48;
        int gate = q >> 4, j = ntt * 16 + (q & 15);
        int src = gate * HH + j;
        bihp[idx] = bih[src];
        bhhp[idx] = bhh[src];
    }
    for (size_t i = (size_t)blockIdx.x * 256 + threadIdx.x; i < (size_t)II * HH;
         i += (size_t)gridDim.x * 256)
        Woutb[i] = f2bf(Wout[i]);
}

__global__ void k_h0(const float* __restrict__ z, const float* __restrict__ Wz,
                     const float* __restrict__ bz, unsigned short* __restrict__ hbuf) {
    int b = blockIdx.x;                 // 256
    int j0 = threadIdx.x * 4;
    const f4v* zr = (const f4v*)(z + (size_t)b * LL);
    u64 packed = 0;
#pragma unroll
    for (int jj = 0; jj < 4; ++jj) {
        int j = j0 + jj;
        const f4v* wr = (const f4v*)(Wz + (size_t)j * LL);
        float s = bz[j];
#pragma unroll
        for (int i = 0; i < LL / 4; ++i) {
            f4v a = zr[i], w = wr[i];
            s += a[0] * w[0] + a[1] * w[1] + a[2] * w[2] + a[3] * w[3];
        }
        packed |= (u64)f2bf(tanhf(s)) << (16 * jj);
    }
    *(u64*)(hbuf + (size_t)b * HH + j0) = packed;
}

// output projection: one 16x16 tile, K=1024 split across 4 waves
template<int FRESH>
__device__ __forceinline__ void proj_tile(
    const unsigned short* hb, const unsigned short* __restrict__ Woutb,
    float* __restrict__ out, float (*pred)[16 * PP],
    int brow, int io, int wave, int lane, int lr, int lk, int tp, float boutv) {
    f32x4 oa = {0.f, 0.f, 0.f, 0.f};
    const unsigned short* ap = hb + (size_t)(brow + lr) * HH + (wave << 8) + lk;
    const unsigned short* wp = Woutb + (size_t)(io * 16 + lr) * HH + (wave << 8) + lk;
#pragma unroll
    for (int ks = 0; ks < 8; ++ks) {
        s8v a = ld16h<FRESH>(ap + ks * 32);
        s8v w = *(const s8v*)(wp + ks * 32);
        oa = __builtin_amdgcn_mfma_f32_16x16x32_bf16(a, w, oa, 0, 0, 0);
    }
    if (wave >= 1) {
#pragma unroll
        for (int r = 0; r < 4; ++r)
            pred[wave - 1][(((lane >> 4) << 2) + r) * PP + lr] = oa[r];
    }
    __syncthreads();
    if (wave == 0) {
#pragma unroll
        for (int r = 0; r < 4; ++r) {
            int rw = ((lane >> 4) << 2) + r;
            int idx = rw * PP + lr;
            float v = oa[r] + pred[0][idx] + pred[1][idx] + pred[2][idx] + boutv;
            out[(size_t)(brow + rw) * (TT * II) + (size_t)tp * II + io * 16 + lr] = sigm(v);
        }
    }
}

// grid 512 = 8 m-groups (32 batches) x 64 nt (16 hidden j -> 48 gate rows)
template<int FRESH>
__device__ void run(const float* __restrict__ tgt, const unsigned short* __restrict__ Wperm,
                    const float* __restrict__ bihp, const float* __restrict__ bhhp,
                    unsigned short* hbuf, const unsigned short* __restrict__ Woutb,
                    const float* __restrict__ bout, float* __restrict__ out,
                    unsigned* flags,
                    float (*red)[32 * RP], float* gxn, float (*pred)[16 * PP]) {
    const int tid = threadIdx.x;
    const int wave = tid >> 6, lane = tid & 63;
    const int lr = lane & 15;
    const int lk = (lane >> 4) << 3;
    const int bid = blockIdx.x;
    const int m = bid & 7, nt = bid >> 3;
    const int doproj = (nt < 32);
    const int brow = m * 32 + ((nt >> 4) & 1) * 16;
    const int io = nt & 15;
    const float boutv = bout[io * 16 + lr];

    // epilogue ownership: batch eb (0..31), 2 consecutive j at j2
    const int eb = tid & 31, j2 = (tid >> 5) << 1;
    const int ob = nt * 48;
    float bir[2], biz[2], bixn[2], bihn[2];
#pragma unroll
    for (int jj = 0; jj < 2; ++jj) {
        int j = j2 + jj;
        bir[jj]  = bihp[ob + j] + bhhp[ob + j];
        biz[jj]  = bihp[ob + 16 + j] + bhhp[ob + 16 + j];
        bixn[jj] = bihp[ob + 32 + j];
        bihn[jj] = bhhp[ob + 32 + j];
    }

    // hoist W slice into registers: 30 x 16B per lane
    s8v wreg[30];
    if (wave == 3) {
#pragma unroll
        for (int ks = 0; ks < 2; ++ks)
#pragma unroll
            for (int ni = 0; ni < 3; ++ni)
                wreg[ks * 3 + ni] = *(const s8v*)(Wperm +
                    (size_t)(nt * 48 + ni * 16 + lr) * K1 + 960 + ks * 32 + lk);
#pragma unroll
        for (int ks = 0; ks < 8; ++ks)
#pragma unroll
            for (int ni = 0; ni < 3; ++ni)
                wreg[6 + ks * 3 + ni] = *(const s8v*)(Wperm +
                    (size_t)(nt * 48 + ni * 16 + lr) * K1 + HH + ks * 32 + lk);
    } else {
#pragma unroll
        for (int ks = 0; ks < 10; ++ks)
#pragma unroll
            for (int ni = 0; ni < 3; ++ni)
                wreg[ks * 3 + ni] = *(const s8v*)(Wperm +
                    (size_t)(nt * 48 + ni * 16 + lr) * K1 + wave * 320 + ks * 32 + lk);
    }

    unsigned* gflags = flags + (m << 6);

    for (int t = 0; t < TT; ++t) {
        const unsigned short* hcur = hbuf + (size_t)(FRESH ? t : (t % 3)) * (BB * HH);
        unsigned short* hnxt = hbuf + (size_t)(FRESH ? (t + 1) : ((t + 1) % 3)) * (BB * HH);

        f32x4 acc[6];
#pragma unroll
        for (int i = 0; i < 6; ++i) acc[i] = (f32x4){0.f, 0.f, 0.f, 0.f};
        f32x4 accx[2];
        accx[0] = (f32x4){0.f, 0.f, 0.f, 0.f};
        accx[1] = (f32x4){0.f, 0.f, 0.f, 0.f};

        // wave 3: x-part GEMM BEFORE the barrier (depends only on constant X)
        if (wave == 3) {
#pragma unroll
            for (int cx = 0; cx < 4; ++cx) {
                s8v xa[2][2];
#pragma unroll
                for (int i2 = 0; i2 < 2; ++i2) {
                    int ks = cx * 2 + i2;
#pragma unroll
                    for (int mi = 0; mi < 2; ++mi)
                        xa[i2][mi] = cvt8(tgt +
                            ((size_t)(m * 32 + mi * 16 + lr) * TT + t) * II + ks * 32 + lk);
                }
#pragma unroll
                for (int i2 = 0; i2 < 2; ++i2) {
                    int ks = cx * 2 + i2;
#pragma unroll
                    for (int mi = 0; mi < 2; ++mi) {
                        acc[mi * 3 + 0] = __builtin_amdgcn_mfma_f32_16x16x32_bf16(
                            xa[i2][mi], wreg[6 + ks * 3 + 0], acc[mi * 3 + 0], 0, 0, 0);
                        acc[mi * 3 + 1] = __builtin_amdgcn_mfma_f32_16x16x32_bf16(
                            xa[i2][mi], wreg[6 + ks * 3 + 1], acc[mi * 3 + 1], 0, 0, 0);
                        accx[mi] = __builtin_amdgcn_mfma_f32_16x16x32_bf16(
                            xa[i2][mi], wreg[6 + ks * 3 + 2], accx[mi], 0, 0, 0);
                    }
                }
            }
        }

        // wait for h_t: every WG of this group has flag >= t (no RMW contention)
        if (t > 0 && wave == 0) {
            int guard = 0;
            for (;;) {
                unsigned v = __hip_atomic_load(gflags + lane, __ATOMIC_RELAXED,
                                               __HIP_MEMORY_SCOPE_AGENT);
                if (__ballot(v >= (unsigned)t) == ~0ull) break;
                __builtin_amdgcn_s_sleep(1);
                if (++guard > (1 << 18)) break;   // safety valve
            }
            asm volatile("" ::: "memory");
        }
        __syncthreads();

        if (wave < 3) {
#pragma unroll
            for (int c = 0; c < 2; ++c) {
                s8v a[5][2];
#pragma unroll
                for (int i = 0; i < 5; ++i)
#pragma unroll
                    for (int mi = 0; mi < 2; ++mi)
                        a[i][mi] = ld16h<FRESH>(hcur +
                            (size_t)(m * 32 + mi * 16 + lr) * HH + wave * 320 + (c * 5 + i) * 32 + lk);
#pragma unroll
                for (int i = 0; i < 5; ++i)
#pragma unroll
                    for (int mi = 0; mi < 2; ++mi)
#pragma unroll
                        for (int ni = 0; ni < 3; ++ni)
                            acc[mi * 3 + ni] = __builtin_amdgcn_mfma_f32_16x16x32_bf16(
                                a[i][mi], wreg[(c * 5 + i) * 3 + ni], acc[mi * 3 + ni], 0, 0, 0);
            }
        } else {
            s8v a[2][2];
#pragma unroll
            for (int ks = 0; ks < 2; ++ks)
#pragma unroll
                for (int mi = 0; mi < 2; ++mi)
                    a[ks][mi] = ld16h<FRESH>(hcur +
                        (size_t)(m * 32 + mi * 16 + lr) * HH + 960 + ks * 32 + lk);
#pragma unroll
            for (int ks = 0; ks < 2; ++ks)
#pragma unroll
                for (int mi = 0; mi < 2; ++mi)
#pragma unroll
                    for (int ni = 0; ni < 3; ++ni)
                        acc[mi * 3 + ni] = __builtin_amdgcn_mfma_f32_16x16x32_bf16(
                            a[ks][mi], wreg[ks * 3 + ni], acc[mi * 3 + ni], 0, 0, 0);
#pragma unroll
            for (int mi = 0; mi < 2; ++mi)
#pragma unroll
                for (int r = 0; r < 4; ++r)
                    gxn[(mi * 16 + ((lane >> 4) << 2) + r) * GP + lr] = accx[mi][r];
        }

        // cross-wave reduce
        if (wave >= 1) {
            float* s = &red[wave - 1][0];
#pragma unroll
            for (int mi = 0; mi < 2; ++mi)
#pragma unroll
                for (int ni = 0; ni < 3; ++ni)
#pragma unroll
                    for (int r = 0; r < 4; ++r)
                        s[(mi * 16 + ((lane >> 4) << 2) + r) * RP + ni * 16 + lr] =
                            acc[mi * 3 + ni][r];
        }
        __syncthreads();
        if (wave == 0) {
#pragma unroll
            for (int mi = 0; mi < 2; ++mi)
#pragma unroll
                for (int ni = 0; ni < 3; ++ni)
#pragma unroll
                    for (int r = 0; r < 4; ++r) {
                        int idx = (mi * 16 + ((lane >> 4) << 2) + r) * RP + ni * 16 + lr;
                        red[0][idx] = acc[mi * 3 + ni][r] + red[0][idx] + red[1][idx] + red[2][idx];
                    }
        }
        __syncthreads();

        // gate epilogue: thread (eb, j2..j2+1) -> one packed 4B h store (sc1)
        {
            const int bg = m * 32 + eb;
            const int jg = nt * 16 + j2;
            unsigned hold = ld4h<FRESH>(hcur + (size_t)bg * HH + jg);
            unsigned packed = 0;
#pragma unroll
            for (int jj = 0; jj < 2; ++jj) {
                int c = j2 + jj;
                float ghr = red[0][eb * RP + c];
                float ghz = red[0][eb * RP + 16 + c];
                float ghn = red[0][eb * RP + 32 + c];
                float gx  = gxn[eb * GP + c];
                float r   = sigm(ghr + bir[jj]);
                float zg  = sigm(ghz + biz[jj]);
                float n   = tanhf(gx + bixn[jj] + r * (ghn + bihn[jj]));
                float ho  = bf2f((unsigned short)(hold >> (16 * jj)));
                packed |= (unsigned)f2bf((1.f - zg) * n + zg * ho) << (16 * jj);
            }
            st4h(hnxt + (size_t)bg * HH + jg, packed);
        }

        // arrive: drain stores, block-sync, one flag STORE per WG
        asm volatile("s_waitcnt vmcnt(0)" ::: "memory");
        __syncthreads();
        if (tid == 0)
            __hip_atomic_store(gflags + nt, (unsigned)(t + 1), __ATOMIC_RELAXED,
                               __HIP_MEMORY_SCOPE_AGENT);

        // project y_{t-1} from h_t while peers' flags fill
        if (doproj && t > 0)
            proj_tile<FRESH>(hcur, Woutb, out, pred, brow, io, wave, lane, lr, lk, t - 1, boutv);
    }

    // tail: y_{T-1} from h_T
    if (doproj) {
        if (wave == 0) {
            int guard = 0;
            for (;;) {
                unsigned v = __hip_atomic_load(gflags + lane, __ATOMIC_RELAXED,
                                               __HIP_MEMORY_SCOPE_AGENT);
                if (__ballot(v >= (unsigned)TT) == ~0ull) break;
                __builtin_amdgcn_s_sleep(1);
                if (++guard > (1 << 18)) break;
            }
            asm volatile("" ::: "memory");
        }
        __syncthreads();
        proj_tile<FRESH>(hbuf + (size_t)(FRESH ? TT : (TT % 3)) * (BB * HH),
                         Woutb, out, pred, brow, io, wave, lane, lr, lk, TT - 1, boutv);
    }
}

__global__ __launch_bounds__(256, 2) void dec_main(
    const float* __restrict__ tgt, const unsigned short* __restrict__ Wperm,
    const float* __restrict__ bihp, const float* __restrict__ bhhp,
    unsigned short* hbuf, const unsigned short* __restrict__ Woutb,
    const float* __restrict__ bout, float* __restrict__ out,
    unsigned* flags, int fresh) {
    __shared__ float red[3][32 * RP];
    __shared__ float gxn[32 * GP];
    __shared__ float pred[3][16 * PP];
    if (fresh)
        run<1>(tgt, Wperm, bihp, bhhp, hbuf, Woutb, bout, out, flags, red, gxn, pred);
    else
        run<0>(tgt, Wperm, bihp, bhhp, hbuf, Woutb, bout, out, flags, red, gxn, pred);
}

extern "C" void kernel_launch(void* const* d_in, const int* in_sizes, int n_in,
                              void* d_out, int out_size, void* d_ws, size_t ws_size,
                              hipStream_t stream) {
    const float* z    = (const float*)d_in[0];
    const float* tgt  = (const float*)d_in[2];
    const float* Wz2h = (const float*)d_in[3];
    const float* bz2h = (const float*)d_in[4];
    const float* Wih  = (const float*)d_in[5];
    const float* Whh  = (const float*)d_in[6];
    const float* bih  = (const float*)d_in[7];
    const float* bhh  = (const float*)d_in[8];
    const float* Wout = (const float*)d_in[9];
    const float* bout = (const float*)d_in[10];
    float* out = (float*)d_out;

    char* ws = (char*)d_ws;
    unsigned short* Wperm = (unsigned short*)ws;               // 7,864,320
    float* bihp           = (float*)(ws + 7864320);            //    12,288
    float* bhhp           = (float*)(ws + 7876608);            //    12,288
    unsigned short* Woutb = (unsigned short*)(ws + 7888896);   //   524,288
    unsigned* flags       = (unsigned*)(ws + 8413184);         //     2,048 (8 grp x 64)
    unsigned short* hbuf  = (unsigned short*)(ws + 8415232);   // 257 or 3 slots x 524,288

    const size_t need_big = 8415232ull + 257ull * 524288ull;   // ~143.1 MB
    const int fresh = (ws_size >= need_big) ? 1 : 0;

    hipMemsetAsync((void*)flags, 0, 2048, stream);
    hipLaunchKernelGGL(k_prep_w, dim3(GN), dim3(256), 0, stream, Whh, Wih, Wperm);
    hipLaunchKernelGGL(k_prep_misc, dim3(1024), dim3(256), 0, stream, bih, bhh, Wout,
                       bihp, bhhp, Woutb);
    hipLaunchKernelGGL(k_h0, dim3(BB), dim3(256), 0, stream, z, Wz2h, bz2h, hbuf);
    hipLaunchKernelGGL(dec_main, dim3(512), dim3(256), 0, stream,
                       tgt, Wperm, bihp, bhhp, hbuf, Woutb, bout, out, flags, fresh);
}